// Round 11
// baseline (318.305 us; speedup 1.0000x reference)
//
#include <hip/hip_runtime.h>
#include <cstddef>

#define NB 16384
#define ITER 4
#define TS 720    // act batch stride in halves (10 slots * 72)

typedef __attribute__((ext_vector_type(8))) _Float16 half8;
typedef __attribute__((ext_vector_type(4))) _Float16 half4;
typedef __attribute__((ext_vector_type(4))) float f32x4;
typedef __attribute__((ext_vector_type(2))) float f32x2;
typedef __attribute__((ext_vector_type(16))) float f32x16;

// ---- ws float offsets ----
#define OFF_W1T 0
#define OFF_SC1 768
#define OFF_SH1 832
#define OFF_SC2 896
#define OFF_SH2 960
#define OFF_SC3 1024
#define OFF_SH3 1088
#define OFF_PB  1152
#define OFF_PBB 1216
#define OFF_W2H 2304                   // w2 hi 10240 f, then lo 10240 f (contiguous)
#define OFF_W2L 12544
#define OFF_W3H 22784                  // w3 hi 14336 f, then lo 14336 f (contiguous)
#define OFF_W3L 37120
#define OFF_SF  51456                  // NB*64
#define OFF_H   (51456 + NB*64)        // NB*16 -> ends 1362176
#define OFF_TF  1362176                // tail frags: 31744 halves = 15872 floats
#define OFF_A2  1378048                // act2 global roundtrip (2 planes x NB*640 halves)
#define WS_NEED ((size_t)11863808 * 4) // bytes required for split-conv path

// tail frag half-offsets within OFF_TF region
#define G1H 0
#define G1L 8192
#define G2H 16384
#define G2L 20480
#define H1H 24576
#define H1L 26624
#define H2H 28672
#define H2L 29184
#define COH 29696
#define COL 30720
#define TFH 31744   // total halves

static __device__ __forceinline__ f32x16 mfma32(half8 a, half8 b, f32x16 c) {
  return __builtin_amdgcn_mfma_f32_32x32x16_f16(a, b, c, 0, 0, 0);
}
static __device__ __forceinline__ f32x4 mfma16(half4 a, half4 b, f32x4 c) {
  return __builtin_amdgcn_mfma_f32_16x16x16f16(a, b, c, 0, 0, 0);
}
static __device__ __forceinline__ f32x4 mfma16k32(half8 a, half8 b, f32x4 c) {
  return __builtin_amdgcn_mfma_f32_16x16x32_f16(a, b, c, 0, 0, 0);
}

// ============================ prep ============================
__global__ __launch_bounds__(256) void prep_kernel(
    const float* __restrict__ conv1_w, const float* __restrict__ conv1_b,
    const float* __restrict__ conv2_w, const float* __restrict__ conv2_b,
    const float* __restrict__ conv3_w, const float* __restrict__ conv3_b,
    const float* __restrict__ bn1_g, const float* __restrict__ bn1_b,
    const float* __restrict__ bn2_g, const float* __restrict__ bn2_b,
    const float* __restrict__ bn3_g, const float* __restrict__ bn3_b,
    const float* __restrict__ proj_w, const float* __restrict__ proj_b,
    const float* __restrict__ A, const float* __restrict__ Bm,
    const float* __restrict__ Cm, const float* __restrict__ out_w,
    const float* __restrict__ g1_w, const float* __restrict__ g2_w,
    const float* __restrict__ h1_w, const float* __restrict__ h2_w,
    float* __restrict__ ws)
{
  int tid = blockIdx.x * blockDim.x + threadIdx.x;
  int nt = gridDim.x * blockDim.x;
  const float s = rsqrtf(1.0f + 1e-5f);

  for (int i = tid; i < 64*12; i += nt) {
    int o = i & 63, rk = i >> 6;
    ws[OFF_W1T + i] = conv1_w[o*12 + rk];
  }
  for (int o = tid; o < 64; o += nt) {
    float s1 = bn1_g[o]*s, s2 = bn2_g[o]*s, s3 = bn3_g[o]*s;
    ws[OFF_SC1+o] = s1; ws[OFF_SH1+o] = s1*conv1_b[o] + bn1_b[o];
    ws[OFF_SC2+o] = s2; ws[OFF_SH2+o] = s2*conv2_b[o] + bn2_b[o];
    ws[OFF_SC3+o] = s3; ws[OFF_SH3+o] = s3*conv3_b[o] + bn3_b[o];
  }
  // conv2 A-fragments (32x32x16), hi/lo split
  {
    _Float16* w2h = (_Float16*)(ws + OFF_W2H);
    _Float16* w2l = (_Float16*)(ws + OFF_W2L);
    for (int i = tid; i < 20*2*64; i += nt) {
      int lane = i & 63, ot = (i >> 6) & 1, sk = i >> 7;
      int tap = sk >> 2, ic0 = (sk & 3)*16 + (lane >> 5)*8;
      int o = ot*32 + (lane & 31);
      #pragma unroll
      for (int j = 0; j < 8; ++j) {
        float w = conv2_w[o*320 + (ic0 + j)*5 + tap];
        _Float16 hi = (_Float16)w;
        w2h[(size_t)i*8 + j] = hi;
        w2l[(size_t)i*8 + j] = (_Float16)(w - (float)hi);
      }
    }
  }
  {
    _Float16* w3h = (_Float16*)(ws + OFF_W3H);
    _Float16* w3l = (_Float16*)(ws + OFF_W3L);
    for (int i = tid; i < 28*2*64; i += nt) {
      int lane = i & 63, ot = (i >> 6) & 1, sk = i >> 7;
      int tap = sk >> 2, ic0 = (sk & 3)*16 + (lane >> 5)*8;
      int o = ot*32 + (lane & 31);
      #pragma unroll
      for (int j = 0; j < 8; ++j) {
        float w = conv3_w[o*448 + (ic0 + j)*7 + tap];
        _Float16 hi = (_Float16)w;
        w3h[(size_t)i*8 + j] = hi;
        w3l[(size_t)i*8 + j] = (_Float16)(w - (float)hi);
      }
    }
  }
  // PB[c][j], PBB[j]
  for (int i = tid; i < 64; i += nt) {
    int c = i >> 4, j = i & 15;
    float acc = 0.f;
    for (int m = 0; m < 64; ++m) acc += proj_w[c*64+m]*Bm[m*16+j];
    ws[OFF_PB + i] = acc;
  }
  for (int j = tid; j < 16; j += nt) {
    float acc = 0.f;
    for (int m = 0; m < 64; ++m) acc += proj_b[m]*Bm[m*16+j];
    ws[OFF_PBB + j] = acc;
  }

  // ---- tail MFMA fragments (hi/lo) ----
  _Float16* tf = (_Float16*)(ws + OFF_TF);
  for (int i = tid; i < 16*64; i += nt) {
    int l = i & 63, f = i >> 6, mt = f >> 2, ks = f & 3;
    int o = mt*16 + (l & 15), kb = ks*32 + (l >> 4)*8;
    #pragma unroll
    for (int j = 0; j < 8; ++j) {
      float w = g1_w[(size_t)(kb + j)*64 + o];
      _Float16 hi = (_Float16)w;
      tf[G1H + (size_t)i*8 + j] = hi;
      tf[G1L + (size_t)i*8 + j] = (_Float16)(w - (float)hi);
    }
  }
  for (int i = tid; i < 8*64; i += nt) {
    int l = i & 63, f = i >> 6, mt = f >> 1, ks = f & 1;
    int o = mt*16 + (l & 15), kb = ks*32 + (l >> 4)*8;
    #pragma unroll
    for (int j = 0; j < 8; ++j) {
      float w = g2_w[(size_t)(kb + j)*64 + o];
      _Float16 hi = (_Float16)w;
      tf[G2H + (size_t)i*8 + j] = hi;
      tf[G2L + (size_t)i*8 + j] = (_Float16)(w - (float)hi);
    }
  }
  for (int i = tid; i < 4*64; i += nt) {
    int l = i & 63, f = i >> 6, mt = f >> 1, ks = f & 1;
    int hx = mt*16 + (l & 15), kb = ks*32 + (l >> 4)*8;
    #pragma unroll
    for (int j = 0; j < 8; ++j) {
      float w = h1_w[(size_t)(kb + j)*32 + hx];
      _Float16 hi = (_Float16)w;
      tf[H1H + (size_t)i*8 + j] = hi;
      tf[H1L + (size_t)i*8 + j] = (_Float16)(w - (float)hi);
    }
  }
  for (int i = tid; i < 64; i += nt) {
    int l = i, m = l & 15, kb = (l >> 4)*8;
    #pragma unroll
    for (int j = 0; j < 8; ++j) {
      float w = (m < 3) ? h2_w[(size_t)(kb + j)*3 + m] : 0.f;
      _Float16 hi = (_Float16)w;
      tf[H2H + (size_t)i*8 + j] = hi;
      tf[H2L + (size_t)i*8 + j] = (_Float16)(w - (float)hi);
    }
  }
  for (int i = tid; i < 4*64; i += nt) {
    int l = i & 63, mt = i >> 6;
    int o = mt*16 + (l & 15), kb = (l >> 4)*4;
    #pragma unroll
    for (int j = 0; j < 4; ++j) {
      float acc = 0.f;
      for (int m = 0; m < 64; ++m) acc += Cm[(kb + j)*64 + m]*out_w[m*64 + o];
      _Float16 hi = (_Float16)acc;
      tf[COH + (size_t)i*4 + j] = hi;
      tf[COL + (size_t)i*4 + j] = (_Float16)(acc - (float)hi);
    }
  }
}

// ============================ conv12 + fused RNN (split path) ============================
// 1024 thr = 16 waves. Conv blocks (blockIdx < NB/16): 16 batches, wave =
// (pair p = wid>>1, otile ot = wid&1) -> 4 waves/SIMD at 125 KB LDS.
// RNN blocks (blockIdx >= NB/16): register-resident 16x16x16 MFMA rnn.
__global__ __launch_bounds__(1024) void conv12_kernel(
    const float* __restrict__ x, const float* __restrict__ wsr,
    _Float16* __restrict__ a2gh, _Float16* __restrict__ a2gl,
    const float* __restrict__ A, float* __restrict__ hout)
{
  __shared__ __align__(16) _Float16 sW[40960];
  __shared__ __align__(16) _Float16 a1h[16][TS], a1l[16][TS];

  const int tid = threadIdx.x;
  const int lane = tid & 63;
  const int wid = tid >> 6;

  if (blockIdx.x >= NB/16) {
    // ---------------- RNN ----------------
    const int colb = lane & 15;
    const int q = lane >> 4;
    const size_t b = ((size_t)(blockIdx.x - NB/16)*16 + wid)*16 + colb;

    const f32x4 av = *(const f32x4*)(A + (size_t)(lane & 15)*16 + q*4);
    half4 Ahi, Alo;
    #pragma unroll
    for (int j = 0; j < 4; ++j) {
      _Float16 hi = (_Float16)av[j];
      Ahi[j] = hi;
      Alo[j] = (_Float16)(av[j] - (float)hi);
    }
    f32x4 pb0 = *(const f32x4*)(wsr + OFF_PB + 0*16 + q*4);
    f32x4 pb1 = *(const f32x4*)(wsr + OFF_PB + 1*16 + q*4);
    f32x4 pb2 = *(const f32x4*)(wsr + OFF_PB + 2*16 + q*4);
    f32x4 pb3 = *(const f32x4*)(wsr + OFF_PB + 3*16 + q*4);
    f32x4 pbb = *(const f32x4*)(wsr + OFF_PBB + q*4);

    const float* xb = x + b*400;
    half4 hh = {}, hl = {};
    f32x4 hf;
    #pragma unroll 2
    for (int t = 0; t < 100; ++t) {
      const f32x4 xv = *(const f32x4*)(xb + t*4);
      f32x4 U;
      #pragma unroll
      for (int r = 0; r < 4; ++r)
        U[r] = pbb[r] + xv[0]*pb0[r] + xv[1]*pb1[r] + xv[2]*pb2[r] + xv[3]*pb3[r];
      f32x4 u = mfma16(Alo, hh, U);
      u = mfma16(Ahi, hl, u);
      u = mfma16(Ahi, hh, u);
      #pragma unroll
      for (int r = 0; r < 4; ++r) {
        float e = __expf(2.f*u[r]);
        float hn = 1.f - 2.f/(e + 1.f);
        hf[r] = hn;
        _Float16 hi = (_Float16)hn;
        hh[r] = hi;
        hl[r] = (_Float16)(hn - (float)hi);
      }
    }
    *(f32x4*)(hout + b*16 + q*4) = hf;
    return;
  }

  // ---------------- conv1 + conv2 ----------------
  const int n = lane & 15;
  const int nc = (n < 10) ? n : 9;
  const int kh8 = (lane >> 5) * 8;
  const int rq = 4 * (lane >> 5);
  const int p = wid >> 1;
  const int ot = wid & 1;
  const int lbL = 2*p + ((lane >> 4) & 1);
  const half8 z8 = {};
  const size_t B0g = (size_t)blockIdx.x * 16;

  { // stage w2 hi+lo (contiguous in ws)
    const f32x4* src = (const f32x4*)(wsr + OFF_W2H);
    f32x4* dst = (f32x4*)sW;
    for (int i = tid; i < 5120; i += 1024) dst[i] = src[i];
  }
  { // conv1: wave wid handles batch B0g + wid
    const float sc1 = wsr[OFF_SC1 + lane], sh1 = wsr[OFF_SH1 + lane];
    const size_t gb = B0g + wid;
    float xv[4][12];
    #pragma unroll
    for (int c = 0; c < 4; ++c) { xv[c][0] = 0.f; xv[c][11] = 0.f; }
    #pragma unroll
    for (int tt = 0; tt < 10; ++tt)
      #pragma unroll
      for (int c = 0; c < 4; ++c)
        xv[c][1 + tt] = x[gb*400 + (90 + tt)*4 + c];
    float a1[10];
    #pragma unroll
    for (int t = 0; t < 10; ++t) a1[t] = 0.f;
    #pragma unroll
    for (int c = 0; c < 4; ++c)
      #pragma unroll
      for (int k = 0; k < 3; ++k) {
        const float wv = wsr[OFF_W1T + (c*3 + k)*64 + lane];
        #pragma unroll
        for (int t = 0; t < 10; ++t) a1[t] += wv * xv[c][t + k];
      }
    #pragma unroll
    for (int t = 0; t < 10; ++t) {
      float v = sc1*a1[t] + sh1;
      v = v > 0.f ? v : 0.f;
      _Float16 hi = (_Float16)v;
      a1h[wid][t*72 + lane] = hi;
      a1l[wid][t*72 + lane] = (_Float16)(v - (float)hi);
    }
  }
  __syncthreads();

  // conv2: this wave's pair, otile ot only
  {
    f32x16 acc;
    #pragma unroll
    for (int r = 0; r < 16; ++r) acc[r] = 0.f;
    const _Float16* bhp = &a1h[lbL][0];
    const _Float16* blp = &a1l[lbL][0];
    #pragma unroll
    for (int sk = 0; sk < 20; ++sk) {
      const int tap = sk >> 2, icb = (sk & 3)*16;
      const int t = nc + tap - 2;
      const int tc = t < 0 ? 0 : (t > 9 ? 9 : t);
      const bool valid = (t >= 0) & (t <= 9);
      const int off = tc*72 + icb + kh8;
      half8 bh = *(const half8*)(bhp + off);
      half8 bl = *(const half8*)(blp + off);
      bh = valid ? bh : z8;
      bl = valid ? bl : z8;
      const half8 wh = *(const half8*)(sW + (size_t)(sk*2 + ot)*512 + lane*8);
      const half8 wl = *(const half8*)(sW + (size_t)(40 + sk*2 + ot)*512 + lane*8);
      acc = mfma32(wh, bh, acc);
      acc = mfma32(wh, bl, acc);
      acc = mfma32(wl, bh, acc);
    }
    if (n < 10) {
      const size_t gb = B0g + lbL;
      #pragma unroll
      for (int q = 0; q < 4; ++q) {
        const int rowb = 8*q + rq + ot*32;
        const f32x4 sc = *(const f32x4*)(wsr + OFF_SC2 + rowb);
        const f32x4 sh = *(const f32x4*)(wsr + OFF_SH2 + rowb);
        half4 h4, l4;
        #pragma unroll
        for (int r = 0; r < 4; ++r) {
          float v = sc[r]*acc[4*q + r] + sh[r];
          v = v > 0.f ? v : 0.f;
          _Float16 hi = (_Float16)v;
          h4[r] = hi;
          l4[r] = (_Float16)(v - (float)hi);
        }
        *(half4*)(a2gh + gb*640 + n*64 + rowb) = h4;
        *(half4*)(a2gl + gb*640 + n*64 + rowb) = l4;
      }
    }
  }
}

// ============================ conv3 (split path) ============================
// 1024 thr = 16 waves, wave = (pair, otile); 16 batches/block; grid NB/16.
// LDS: w3 hi+lo 112 KB + a2 h/l 45 KB = 157 KB -> 4 waves/SIMD.
__global__ __launch_bounds__(1024) void conv3k_kernel(
    const float* __restrict__ wsr,
    const _Float16* __restrict__ a2gh, const _Float16* __restrict__ a2gl,
    float* __restrict__ sfp)
{
  __shared__ __align__(16) _Float16 sW[57344];
  __shared__ __align__(16) _Float16 a2h[16][TS], a2l[16][TS];

  const int tid = threadIdx.x;
  const int lane = tid & 63;
  const int wid = tid >> 6;
  const int n = lane & 15;
  const int nc = (n < 10) ? n : 9;
  const int kh8 = (lane >> 5) * 8;
  const int rq = 4 * (lane >> 5);
  const int p = wid >> 1;
  const int ot = wid & 1;
  const int lbL = 2*p + ((lane >> 4) & 1);
  const half8 z8 = {};
  const size_t B0g = (size_t)blockIdx.x * 16;

  { // stage w3 hi+lo
    const f32x4* src = (const f32x4*)(wsr + OFF_W3H);
    f32x4* dst = (f32x4*)sW;
    for (int i = tid; i < 7168; i += 1024) dst[i] = src[i];
  }
  { // stage a2: 2 planes x (16 batches x 80 half8) = 2560 items.
    // r10 BUG: `pl = i>>11, j = i&2047` re-staged the hi plane for
    // i=1024..2047 and left a2l rows 512..1279 as stale LDS -> absmax 604.
    for (int i = tid; i < 2560; i += 1024) {
      const int pl = i / 1280;         // 0: hi, 1: lo
      const int j = i % 1280;
      const int lb = j / 80, rem = (j % 80)*8;
      const int t = rem >> 6, o = rem & 63;
      const half8 v = pl ? *(const half8*)(a2gl + (B0g + lb)*640 + rem)
                         : *(const half8*)(a2gh + (B0g + lb)*640 + rem);
      if (pl) *(half8*)(&a2l[lb][t*72 + o]) = v;
      else    *(half8*)(&a2h[lb][t*72 + o]) = v;
    }
  }
  __syncthreads();

  {
    f32x16 acc;
    #pragma unroll
    for (int r = 0; r < 16; ++r) acc[r] = 0.f;
    const _Float16* bhp = &a2h[lbL][0];
    const _Float16* blp = &a2l[lbL][0];
    #pragma unroll
    for (int sk = 0; sk < 28; ++sk) {
      const int tap = sk >> 2, icb = (sk & 3)*16;
      const int t = nc + tap - 3;
      const int tc = t < 0 ? 0 : (t > 9 ? 9 : t);
      const bool valid = (t >= 0) & (t <= 9);
      const int off = tc*72 + icb + kh8;
      half8 bh = *(const half8*)(bhp + off);
      half8 bl = *(const half8*)(blp + off);
      bh = valid ? bh : z8;
      bl = valid ? bl : z8;
      const half8 wh = *(const half8*)(sW + (size_t)(sk*2 + ot)*512 + lane*8);
      const half8 wl = *(const half8*)(sW + (size_t)(56 + sk*2 + ot)*512 + lane*8);
      acc = mfma32(wh, bh, acc);
      acc = mfma32(wh, bl, acc);
      acc = mfma32(wl, bh, acc);
    }
    #pragma unroll
    for (int q = 0; q < 4; ++q) {
      const int rowb = 8*q + rq + ot*32;
      const f32x4 sc = *(const f32x4*)(wsr + OFF_SC3 + rowb);
      const f32x4 sh = *(const f32x4*)(wsr + OFF_SH3 + rowb);
      f32x4 v;
      #pragma unroll
      for (int r = 0; r < 4; ++r) {
        float t2 = sc[r]*acc[4*q + r] + sh[r];
        t2 = t2 > 0.f ? t2 : 0.f;
        v[r] = (n < 10) ? t2 : 0.f;
      }
      #pragma unroll
      for (int r = 0; r < 4; ++r) {
        v[r] += __shfl_xor(v[r], 1, 16);
        v[r] += __shfl_xor(v[r], 2, 16);
        v[r] += __shfl_xor(v[r], 4, 16);
        v[r] += __shfl_xor(v[r], 8, 16);
      }
      if (n == 0)
        *(f32x4*)(sfp + (B0g + lbL)*64 + rowb) = v * 0.1f;
    }
  }
}

// ============================ conv (fallback: single kernel, r8) ============================
__global__ __launch_bounds__(256) void conv_kernel(
    const float* __restrict__ x, const float* __restrict__ wsr,
    float* __restrict__ sfp)
{
  __shared__ __align__(16) _Float16 sW[57344];
  __shared__ __align__(16) _Float16 a1h[8][TS], a1l[8][TS];
  __shared__ __align__(16) _Float16 a2h[8][TS], a2l[8][TS];

  const int tid = threadIdx.x;
  const int lane = tid & 63;
  const int wid = tid >> 6;
  const int n = lane & 15;
  const int nc = (n < 10) ? n : 9;
  const int kh8 = (lane >> 5) * 8;
  const int rq = 4 * (lane >> 5);
  const int lb0 = (wid >> 1)*4 + (wid & 1)*2;
  const int lbL = lb0 + ((lane >> 4) & 1);
  const half8 z8 = {};
  const float sc1 = wsr[OFF_SC1 + lane], sh1 = wsr[OFF_SH1 + lane];

  for (int it = 0; it < ITER; ++it) {
    const size_t gbase = (size_t)blockIdx.x*(8*ITER) + (size_t)it*8;
    {
      const f32x4* src = (const f32x4*)(wsr + OFF_W2H);
      f32x4* dst = (f32x4*)sW;
      for (int i = tid; i < 5120; i += 256) dst[i] = src[i];
    }
    #pragma unroll
    for (int bb = 0; bb < 2; ++bb) {
      const int lb = lb0 + bb;
      const size_t gb = gbase + lb;
      float xv[4][12];
      #pragma unroll
      for (int c = 0; c < 4; ++c) { xv[c][0] = 0.f; xv[c][11] = 0.f; }
      #pragma unroll
      for (int tt = 0; tt < 10; ++tt)
        #pragma unroll
        for (int c = 0; c < 4; ++c)
          xv[c][1 + tt] = x[gb*400 + (90 + tt)*4 + c];
      float a1[10];
      #pragma unroll
      for (int t = 0; t < 10; ++t) a1[t] = 0.f;
      #pragma unroll
      for (int c = 0; c < 4; ++c)
        #pragma unroll
        for (int k = 0; k < 3; ++k) {
          const float wv = wsr[OFF_W1T + (c*3 + k)*64 + lane];
          #pragma unroll
          for (int t = 0; t < 10; ++t) a1[t] += wv * xv[c][t + k];
        }
      #pragma unroll
      for (int t = 0; t < 10; ++t) {
        float v = sc1*a1[t] + sh1;
        v = v > 0.f ? v : 0.f;
        _Float16 hi = (_Float16)v;
        a1h[lb][t*72 + lane] = hi;
        a1l[lb][t*72 + lane] = (_Float16)(v - (float)hi);
      }
    }
    __syncthreads();
    {
      f32x16 acc0, acc1;
      #pragma unroll
      for (int r = 0; r < 16; ++r) { acc0[r] = 0.f; acc1[r] = 0.f; }
      const _Float16* bhp = &a1h[lbL][0];
      const _Float16* blp = &a1l[lbL][0];
      #pragma unroll
      for (int sk = 0; sk < 20; ++sk) {
        const int tap = sk >> 2, icb = (sk & 3)*16;
        const int t = nc + tap - 2;
        const int tc = t < 0 ? 0 : (t > 9 ? 9 : t);
        const bool valid = (t >= 0) & (t <= 9);
        const int off = tc*72 + icb + kh8;
        half8 bh = *(const half8*)(bhp + off);
        half8 bl = *(const half8*)(blp + off);
        bh = valid ? bh : z8;
        bl = valid ? bl : z8;
        const half8 wh0 = *(const half8*)(sW + (size_t)(sk*2 + 0)*512 + lane*8);
        const half8 wh1 = *(const half8*)(sW + (size_t)(sk*2 + 1)*512 + lane*8);
        const half8 wl0 = *(const half8*)(sW + (size_t)(40 + sk*2)*512 + lane*8);
        const half8 wl1 = *(const half8*)(sW + (size_t)(41 + sk*2)*512 + lane*8);
        acc0 = mfma32(wh0, bh, acc0);
        acc0 = mfma32(wh0, bl, acc0);
        acc0 = mfma32(wl0, bh, acc0);
        acc1 = mfma32(wh1, bh, acc1);
        acc1 = mfma32(wh1, bl, acc1);
        acc1 = mfma32(wl1, bh, acc1);
      }
      if (n < 10) {
        auto epi = [&](const f32x16& ac, int ot) {
          #pragma unroll
          for (int q = 0; q < 4; ++q) {
            const int rowb = 8*q + rq + ot*32;
            const f32x4 sc = *(const f32x4*)(wsr + OFF_SC2 + rowb);
            const f32x4 sh = *(const f32x4*)(wsr + OFF_SH2 + rowb);
            half4 h4, l4;
            #pragma unroll
            for (int r = 0; r < 4; ++r) {
              float v = sc[r]*ac[4*q + r] + sh[r];
              v = v > 0.f ? v : 0.f;
              _Float16 hi = (_Float16)v;
              h4[r] = hi;
              l4[r] = (_Float16)(v - (float)hi);
            }
            *(half4*)(&a2h[lbL][n*72 + rowb]) = h4;
            *(half4*)(&a2l[lbL][n*72 + rowb]) = l4;
          }
        };
        epi(acc0, 0);
        epi(acc1, 1);
      }
    }
    __syncthreads();
    {
      const f32x4* src = (const f32x4*)(wsr + OFF_W3H);
      f32x4* dst = (f32x4*)sW;
      for (int i = tid; i < 7168; i += 256) dst[i] = src[i];
    }
    __syncthreads();
    {
      f32x16 acc0, acc1;
      #pragma unroll
      for (int r = 0; r < 16; ++r) { acc0[r] = 0.f; acc1[r] = 0.f; }
      const _Float16* bhp = &a2h[lbL][0];
      const _Float16* blp = &a2l[lbL][0];
      #pragma unroll
      for (int sk = 0; sk < 28; ++sk) {
        const int tap = sk >> 2, icb = (sk & 3)*16;
        const int t = nc + tap - 3;
        const int tc = t < 0 ? 0 : (t > 9 ? 9 : t);
        const bool valid = (t >= 0) & (t <= 9);
        const int off = tc*72 + icb + kh8;
        half8 bh = *(const half8*)(bhp + off);
        half8 bl = *(const half8*)(blp + off);
        bh = valid ? bh : z8;
        bl = valid ? bl : z8;
        const half8 wh0 = *(const half8*)(sW + (size_t)(sk*2 + 0)*512 + lane*8);
        const half8 wh1 = *(const half8*)(sW + (size_t)(sk*2 + 1)*512 + lane*8);
        const half8 wl0 = *(const half8*)(sW + (size_t)(56 + sk*2)*512 + lane*8);
        const half8 wl1 = *(const half8*)(sW + (size_t)(57 + sk*2)*512 + lane*8);
        acc0 = mfma32(wh0, bh, acc0);
        acc0 = mfma32(wh0, bl, acc0);
        acc0 = mfma32(wl0, bh, acc0);
        acc1 = mfma32(wh1, bh, acc1);
        acc1 = mfma32(wh1, bl, acc1);
        acc1 = mfma32(wl1, bh, acc1);
      }
      auto epi = [&](const f32x16& ac, int ot) {
        #pragma unroll
        for (int q = 0; q < 4; ++q) {
          const int rowb = 8*q + rq + ot*32;
          const f32x4 sc = *(const f32x4*)(wsr + OFF_SC3 + rowb);
          const f32x4 sh = *(const f32x4*)(wsr + OFF_SH3 + rowb);
          f32x4 v;
          #pragma unroll
          for (int r = 0; r < 4; ++r) {
            float t2 = sc[r]*ac[4*q + r] + sh[r];
            t2 = t2 > 0.f ? t2 : 0.f;
            v[r] = (n < 10) ? t2 : 0.f;
          }
          #pragma unroll
          for (int r = 0; r < 4; ++r) {
            v[r] += __shfl_xor(v[r], 1, 16);
            v[r] += __shfl_xor(v[r], 2, 16);
            v[r] += __shfl_xor(v[r], 4, 16);
            v[r] += __shfl_xor(v[r], 8, 16);
          }
          if (n == 0)
            *(f32x4*)(sfp + (gbase + lbL)*64 + rowb) = v * 0.1f;
        }
      };
      epi(acc0, 0);
      epi(acc1, 1);
    }
    __syncthreads();
  }
}

// ============================ RNN (standalone, for fallback path) ============================
__global__ __launch_bounds__(256) void rnn_kernel(
    const float* __restrict__ x, const float* __restrict__ wsr,
    const float* __restrict__ A, float* __restrict__ hout)
{
  const int lane = threadIdx.x & 63;
  const int wid = threadIdx.x >> 6;
  const int colb = lane & 15;
  const int q = lane >> 4;
  const size_t b = ((size_t)blockIdx.x*4 + wid)*16 + colb;

  const f32x4 av = *(const f32x4*)(A + (size_t)(lane & 15)*16 + q*4);
  half4 Ahi, Alo;
  #pragma unroll
  for (int j = 0; j < 4; ++j) {
    _Float16 hi = (_Float16)av[j];
    Ahi[j] = hi;
    Alo[j] = (_Float16)(av[j] - (float)hi);
  }
  f32x4 pb0 = *(const f32x4*)(wsr + OFF_PB + 0*16 + q*4);
  f32x4 pb1 = *(const f32x4*)(wsr + OFF_PB + 1*16 + q*4);
  f32x4 pb2 = *(const f32x4*)(wsr + OFF_PB + 2*16 + q*4);
  f32x4 pb3 = *(const f32x4*)(wsr + OFF_PB + 3*16 + q*4);
  f32x4 pbb = *(const f32x4*)(wsr + OFF_PBB + q*4);

  const float* xb = x + b*400;
  half4 hh = {}, hl = {};
  f32x4 hf;
  #pragma unroll 2
  for (int t = 0; t < 100; ++t) {
    const f32x4 xv = *(const f32x4*)(xb + t*4);
    f32x4 U;
    #pragma unroll
    for (int r = 0; r < 4; ++r)
      U[r] = pbb[r] + xv[0]*pb0[r] + xv[1]*pb1[r] + xv[2]*pb2[r] + xv[3]*pb3[r];
    f32x4 u = mfma16(Alo, hh, U);
    u = mfma16(Ahi, hl, u);
    u = mfma16(Ahi, hh, u);
    #pragma unroll
    for (int r = 0; r < 4; ++r) {
      float e = __expf(2.f*u[r]);
      float hn = 1.f - 2.f/(e + 1.f);
      hf[r] = hn;
      _Float16 hi = (_Float16)hn;
      hh[r] = hi;
      hl[r] = (_Float16)(hn - (float)hi);
    }
  }
  *(f32x4*)(hout + b*16 + q*4) = hf;
}

// ============================ tail (MFMA, 16 batches/wave) ============================
#define CMBH 0
#define CMBL 2176
#define T1H  4352
#define T1L  5504
#define FLH  6656
#define FLL  7808
#define RH   8960
#define RL   9600
__global__ __launch_bounds__(256) void tail_kernel(
    const float* __restrict__ wsr,
    const float* __restrict__ g1_b, const float* __restrict__ g2_b,
    const float* __restrict__ h1_b, const float* __restrict__ h2_b,
    const float* __restrict__ out_b, float* __restrict__ out)
{
  __shared__ __align__(16) _Float16 sWF[TFH];
  __shared__ __align__(16) _Float16 sAct[4*10240];

  const int tid = threadIdx.x;
  const int lane = tid & 63;
  const int wid = tid >> 6;
  const int n = lane & 15;
  const int q = lane >> 4;
  const int B0 = blockIdx.x*64 + wid*16;

  {
    const f32x4* src = (const f32x4*)(wsr + OFF_TF);
    f32x4* dst = (f32x4*)sWF;
    for (int i = tid; i < TFH/8; i += 256) dst[i] = src[i];
  }
  __syncthreads();

  _Float16* wa = sAct + wid*10240;
  const float* sf = wsr + OFF_SF;
  const float* hws = wsr + OFF_H;

  const f32x4 hv = *(const f32x4*)(hws + (size_t)(B0 + n)*16 + q*4);
  half4 hh, hl;
  #pragma unroll
  for (int j = 0; j < 4; ++j) {
    _Float16 hi = (_Float16)hv[j];
    hh[j] = hi;
    hl[j] = (_Float16)(hv[j] - (float)hi);
  }
  f32x4 lc[4];
  #pragma unroll
  for (int mt = 0; mt < 4; ++mt) {
    lc[mt] = *(const f32x4*)(out_b + mt*16 + q*4);
    const half4 ah = *(const half4*)(sWF + COH + (size_t)(mt*64 + lane)*4);
    const half4 al = *(const half4*)(sWF + COL + (size_t)(mt*64 + lane)*4);
    lc[mt] = mfma16(al, hh, lc[mt]);
    lc[mt] = mfma16(ah, hl, lc[mt]);
    lc[mt] = mfma16(ah, hh, lc[mt]);
  }
  f32x4 sfv[4];
  #pragma unroll
  for (int mt = 0; mt < 4; ++mt) {
    sfv[mt] = *(const f32x4*)(sf + (size_t)(B0 + n)*64 + mt*16 + q*4);
    half4 sh4, sl4, lh4, ll4;
    #pragma unroll
    for (int r = 0; r < 4; ++r) {
      _Float16 hi = (_Float16)sfv[mt][r];
      sh4[r] = hi; sl4[r] = (_Float16)(sfv[mt][r] - (float)hi);
      _Float16 hi2 = (_Float16)lc[mt][r];
      lh4[r] = hi2; ll4[r] = (_Float16)(lc[mt][r] - (float)hi2);
    }
    *(half4*)(wa + CMBH + n*136 + mt*16 + q*4) = sh4;
    *(half4*)(wa + CMBL + n*136 + mt*16 + q*4) = sl4;
    *(half4*)(wa + CMBH + n*136 + 64 + mt*16 + q*4) = lh4;
    *(half4*)(wa + CMBL + n*136 + 64 + mt*16 + q*4) = ll4;
  }
  f32x4 u1[4];
  #pragma unroll
  for (int mt = 0; mt < 4; ++mt) u1[mt] = *(const f32x4*)(g1_b + mt*16 + q*4);
  #pragma unroll
  for (int ks = 0; ks < 4; ++ks) {
    const half8 bh = *(const half8*)(wa + CMBH + n*136 + ks*32 + q*8);
    const half8 bl = *(const half8*)(wa + CMBL + n*136 + ks*32 + q*8);
    #pragma unroll
    for (int mt = 0; mt < 4; ++mt) {
      const half8 ah = *(const half8*)(sWF + G1H + (size_t)((mt*4 + ks)*64 + lane)*8);
      const half8 al = *(const half8*)(sWF + G1L + (size_t)((mt*4 + ks)*64 + lane)*8);
      u1[mt] = mfma16k32(al, bh, u1[mt]);
      u1[mt] = mfma16k32(ah, bl, u1[mt]);
      u1[mt] = mfma16k32(ah, bh, u1[mt]);
    }
  }
  #pragma unroll
  for (int mt = 0; mt < 4; ++mt) {
    half4 th4, tl4;
    #pragma unroll
    for (int r = 0; r < 4; ++r) {
      float e = __expf(2.f*u1[mt][r]);
      float t1 = 1.f - 2.f/(e + 1.f);
      _Float16 hi = (_Float16)t1;
      th4[r] = hi; tl4[r] = (_Float16)(t1 - (float)hi);
    }
    *(half4*)(wa + T1H + n*72 + mt*16 + q*4) = th4;
    *(half4*)(wa + T1L + n*72 + mt*16 + q*4) = tl4;
  }
  f32x4 u2[4];
  #pragma unroll
  for (int mt = 0; mt < 4; ++mt) u2[mt] = *(const f32x4*)(g2_b + mt*16 + q*4);
  #pragma unroll
  for (int ks = 0; ks < 2; ++ks) {
    const half8 bh = *(const half8*)(wa + T1H + n*72 + ks*32 + q*8);
    const half8 bl = *(const half8*)(wa + T1L + n*72 + ks*32 + q*8);
    #pragma unroll
    for (int mt = 0; mt < 4; ++mt) {
      const half8 ah = *(const half8*)(sWF + G2H + (size_t)((mt*2 + ks)*64 + lane)*8);
      const half8 al = *(const half8*)(sWF + G2L + (size_t)((mt*2 + ks)*64 + lane)*8);
      u2[mt] = mfma16k32(al, bh, u2[mt]);
      u2[mt] = mfma16k32(ah, bl, u2[mt]);
      u2[mt] = mfma16k32(ah, bh, u2[mt]);
    }
  }
  #pragma unroll
  for (int mt = 0; mt < 4; ++mt) {
    half4 fh4, fl4;
    #pragma unroll
    for (int r = 0; r < 4; ++r) {
      float gate = 1.f/(1.f + __expf(-u2[mt][r]));
      float f = sfv[mt][r] * gate;
      _Float16 hi = (_Float16)f;
      fh4[r] = hi; fl4[r] = (_Float16)(f - (float)hi);
    }
    *(half4*)(wa + FLH + n*72 + mt*16 + q*4) = fh4;
    *(half4*)(wa + FLL + n*72 + mt*16 + q*4) = fl4;
  }
  f32x4 u3[2];
  #pragma unroll
  for (int mt = 0; mt < 2; ++mt) u3[mt] = *(const f32x4*)(h1_b + mt*16 + q*4);
  #pragma unroll
  for (int ks = 0; ks < 2; ++ks) {
    const half8 bh = *(const half8*)(wa + FLH + n*72 + ks*32 + q*8);
    const half8 bl = *(const half8*)(wa + FLL + n*72 + ks*32 + q*8);
    #pragma unroll
    for (int mt = 0; mt < 2; ++mt) {
      const half8 ah = *(const half8*)(sWF + H1H + (size_t)((mt*2 + ks)*64 + lane)*8);
      const half8 al = *(const half8*)(sWF + H1L + (size_t)((mt*2 + ks)*64 + lane)*8);
      u3[mt] = mfma16k32(al, bh, u3[mt]);
      u3[mt] = mfma16k32(ah, bl, u3[mt]);
      u3[mt] = mfma16k32(ah, bh, u3[mt]);
    }
  }
  #pragma unroll
  for (int mt = 0; mt < 2; ++mt) {
    half4 rh4, rl4;
    #pragma unroll
    for (int r = 0; r < 4; ++r) {
      float v = fmaxf(u3[mt][r], 0.f);
      _Float16 hi = (_Float16)v;
      rh4[r] = hi; rl4[r] = (_Float16)(v - (float)hi);
    }
    *(half4*)(wa + RH + n*40 + mt*16 + q*4) = rh4;
    *(half4*)(wa + RL + n*40 + mt*16 + q*4) = rl4;
  }
  {
    f32x4 u4;
    if (q == 0) { u4[0] = h2_b[0]; u4[1] = h2_b[1]; u4[2] = h2_b[2]; u4[3] = 0.f; }
    else { u4[0] = 0.f; u4[1] = 0.f; u4[2] = 0.f; u4[3] = 0.f; }
    const half8 bh = *(const half8*)(wa + RH + n*40 + q*8);
    const half8 bl = *(const half8*)(wa + RL + n*40 + q*8);
    const half8 ah = *(const half8*)(sWF + H2H + (size_t)lane*8);
    const half8 al = *(const half8*)(sWF + H2L + (size_t)lane*8);
    u4 = mfma16k32(al, bh, u4);
    u4 = mfma16k32(ah, bl, u4);
    u4 = mfma16k32(ah, bh, u4);
    if (q == 0) {
      out[(size_t)(B0 + n)*3 + 0] = u4[0];
      out[(size_t)(B0 + n)*3 + 1] = u4[1];
      out[(size_t)(B0 + n)*3 + 2] = u4[2];
    }
  }
}

// ============================ launch ============================
extern "C" void kernel_launch(void* const* d_in, const int* in_sizes, int n_in,
                              void* d_out, int out_size, void* d_ws, size_t ws_size,
                              hipStream_t stream) {
  const float* x       = (const float*)d_in[0];
  const float* conv1_w = (const float*)d_in[1];
  const float* conv1_b = (const float*)d_in[2];
  const float* conv2_w = (const float*)d_in[3];
  const float* conv2_b = (const float*)d_in[4];
  const float* conv3_w = (const float*)d_in[5];
  const float* conv3_b = (const float*)d_in[6];
  const float* bn1_g   = (const float*)d_in[7];
  const float* bn1_b   = (const float*)d_in[8];
  const float* bn2_g   = (const float*)d_in[9];
  const float* bn2_b   = (const float*)d_in[10];
  const float* bn3_g   = (const float*)d_in[11];
  const float* bn3_b   = (const float*)d_in[12];
  const float* proj_w  = (const float*)d_in[13];
  const float* proj_b  = (const float*)d_in[14];
  const float* A       = (const float*)d_in[15];
  const float* Bm      = (const float*)d_in[16];
  const float* Cm      = (const float*)d_in[17];
  const float* out_w   = (const float*)d_in[18];
  const float* out_b   = (const float*)d_in[19];
  const float* g1_w    = (const float*)d_in[20];
  const float* g1_b    = (const float*)d_in[21];
  const float* g2_w    = (const float*)d_in[22];
  const float* g2_b    = (const float*)d_in[23];
  const float* h1_w    = (const float*)d_in[24];
  const float* h1_b    = (const float*)d_in[25];
  const float* h2_w    = (const float*)d_in[26];
  const float* h2_b    = (const float*)d_in[27];
  float* ws = (float*)d_ws;
  float* out = (float*)d_out;

  prep_kernel<<<64, 256, 0, stream>>>(conv1_w, conv1_b, conv2_w, conv2_b,
      conv3_w, conv3_b, bn1_g, bn1_b, bn2_g, bn2_b, bn3_g, bn3_b,
      proj_w, proj_b, A, Bm, Cm, out_w, g1_w, g2_w, h1_w, h2_w, ws);

  if (ws_size >= WS_NEED) {
    _Float16* a2gh = (_Float16*)(ws + OFF_A2);
    _Float16* a2gl = a2gh + (size_t)NB*640;
    conv12_kernel<<<NB/16 + NB/256, 1024, 0, stream>>>(x, ws, a2gh, a2gl,
        A, ws + OFF_H);
    conv3k_kernel<<<NB/16, 1024, 0, stream>>>(ws, a2gh, a2gl, ws + OFF_SF);
  } else {
    conv_kernel<<<NB/(8*ITER), 256, 0, stream>>>(x, ws, ws + OFF_SF);
    rnn_kernel<<<NB/64, 256, 0, stream>>>(x, ws, A, ws + OFF_H);
  }
  tail_kernel<<<NB/64, 256, 0, stream>>>(ws, g1_b, g2_b, h1_b, h2_b, out_b, out);
}

// Round 12
// 275.779 us; speedup vs baseline: 1.1542x; 1.1542x over previous
//
#include <hip/hip_runtime.h>
#include <cstddef>

#define NB 16384
#define ITER 4
#define TS 720    // act batch stride in halves (10 slots * 72)
#define NRNN (NB/128)   // 128 leading rnn blocks in conv12 grid

typedef __attribute__((ext_vector_type(8))) _Float16 half8;
typedef __attribute__((ext_vector_type(4))) _Float16 half4;
typedef __attribute__((ext_vector_type(4))) float f32x4;
typedef __attribute__((ext_vector_type(2))) float f32x2;
typedef __attribute__((ext_vector_type(16))) float f32x16;

// ---- ws float offsets ----
#define OFF_W1T 0
#define OFF_SC1 768
#define OFF_SH1 832
#define OFF_SC2 896
#define OFF_SH2 960
#define OFF_SC3 1024
#define OFF_SH3 1088
#define OFF_PB  1152
#define OFF_PBB 1216
#define OFF_W2H 2304                   // w2 hi 10240 f, then lo 10240 f (contiguous)
#define OFF_W2L 12544
#define OFF_W3H 22784                  // w3 hi 14336 f, then lo 14336 f (contiguous)
#define OFF_W3L 37120
#define OFF_SF  51456                  // NB*64
#define OFF_H   (51456 + NB*64)        // NB*16 -> ends 1362176
#define OFF_TF  1362176                // tail frags: 31744 halves = 15872 floats
#define OFF_A2  1378048                // act2 global roundtrip (2 planes x NB*640 halves)
#define WS_NEED ((size_t)11863808 * 4) // bytes required for split-conv path

// tail frag half-offsets within OFF_TF region
#define G1H 0
#define G1L 8192
#define G2H 16384
#define G2L 20480
#define H1H 24576
#define H1L 26624
#define H2H 28672
#define H2L 29184
#define COH 29696
#define COL 30720
#define TFH 31744   // total halves

static __device__ __forceinline__ f32x16 mfma32(half8 a, half8 b, f32x16 c) {
  return __builtin_amdgcn_mfma_f32_32x32x16_f16(a, b, c, 0, 0, 0);
}
static __device__ __forceinline__ f32x4 mfma16(half4 a, half4 b, f32x4 c) {
  return __builtin_amdgcn_mfma_f32_16x16x16f16(a, b, c, 0, 0, 0);
}
static __device__ __forceinline__ f32x4 mfma16k32(half8 a, half8 b, f32x4 c) {
  return __builtin_amdgcn_mfma_f32_16x16x32_f16(a, b, c, 0, 0, 0);
}

// ============================ prep ============================
__global__ __launch_bounds__(256) void prep_kernel(
    const float* __restrict__ conv1_w, const float* __restrict__ conv1_b,
    const float* __restrict__ conv2_w, const float* __restrict__ conv2_b,
    const float* __restrict__ conv3_w, const float* __restrict__ conv3_b,
    const float* __restrict__ bn1_g, const float* __restrict__ bn1_b,
    const float* __restrict__ bn2_g, const float* __restrict__ bn2_b,
    const float* __restrict__ bn3_g, const float* __restrict__ bn3_b,
    const float* __restrict__ proj_w, const float* __restrict__ proj_b,
    const float* __restrict__ A, const float* __restrict__ Bm,
    const float* __restrict__ Cm, const float* __restrict__ out_w,
    const float* __restrict__ g1_w, const float* __restrict__ g2_w,
    const float* __restrict__ h1_w, const float* __restrict__ h2_w,
    float* __restrict__ ws)
{
  int tid = blockIdx.x * blockDim.x + threadIdx.x;
  int nt = gridDim.x * blockDim.x;
  const float s = rsqrtf(1.0f + 1e-5f);

  for (int i = tid; i < 64*12; i += nt) {
    int o = i & 63, rk = i >> 6;
    ws[OFF_W1T + i] = conv1_w[o*12 + rk];
  }
  for (int o = tid; o < 64; o += nt) {
    float s1 = bn1_g[o]*s, s2 = bn2_g[o]*s, s3 = bn3_g[o]*s;
    ws[OFF_SC1+o] = s1; ws[OFF_SH1+o] = s1*conv1_b[o] + bn1_b[o];
    ws[OFF_SC2+o] = s2; ws[OFF_SH2+o] = s2*conv2_b[o] + bn2_b[o];
    ws[OFF_SC3+o] = s3; ws[OFF_SH3+o] = s3*conv3_b[o] + bn3_b[o];
  }
  // conv2 A-fragments (32x32x16), hi/lo split
  {
    _Float16* w2h = (_Float16*)(ws + OFF_W2H);
    _Float16* w2l = (_Float16*)(ws + OFF_W2L);
    for (int i = tid; i < 20*2*64; i += nt) {
      int lane = i & 63, ot = (i >> 6) & 1, sk = i >> 7;
      int tap = sk >> 2, ic0 = (sk & 3)*16 + (lane >> 5)*8;
      int o = ot*32 + (lane & 31);
      #pragma unroll
      for (int j = 0; j < 8; ++j) {
        float w = conv2_w[o*320 + (ic0 + j)*5 + tap];
        _Float16 hi = (_Float16)w;
        w2h[(size_t)i*8 + j] = hi;
        w2l[(size_t)i*8 + j] = (_Float16)(w - (float)hi);
      }
    }
  }
  {
    _Float16* w3h = (_Float16*)(ws + OFF_W3H);
    _Float16* w3l = (_Float16*)(ws + OFF_W3L);
    for (int i = tid; i < 28*2*64; i += nt) {
      int lane = i & 63, ot = (i >> 6) & 1, sk = i >> 7;
      int tap = sk >> 2, ic0 = (sk & 3)*16 + (lane >> 5)*8;
      int o = ot*32 + (lane & 31);
      #pragma unroll
      for (int j = 0; j < 8; ++j) {
        float w = conv3_w[o*448 + (ic0 + j)*7 + tap];
        _Float16 hi = (_Float16)w;
        w3h[(size_t)i*8 + j] = hi;
        w3l[(size_t)i*8 + j] = (_Float16)(w - (float)hi);
      }
    }
  }
  // PB[c][j], PBB[j]
  for (int i = tid; i < 64; i += nt) {
    int c = i >> 4, j = i & 15;
    float acc = 0.f;
    for (int m = 0; m < 64; ++m) acc += proj_w[c*64+m]*Bm[m*16+j];
    ws[OFF_PB + i] = acc;
  }
  for (int j = tid; j < 16; j += nt) {
    float acc = 0.f;
    for (int m = 0; m < 64; ++m) acc += proj_b[m]*Bm[m*16+j];
    ws[OFF_PBB + j] = acc;
  }

  // ---- tail MFMA fragments (hi/lo) ----
  _Float16* tf = (_Float16*)(ws + OFF_TF);
  for (int i = tid; i < 16*64; i += nt) {
    int l = i & 63, f = i >> 6, mt = f >> 2, ks = f & 3;
    int o = mt*16 + (l & 15), kb = ks*32 + (l >> 4)*8;
    #pragma unroll
    for (int j = 0; j < 8; ++j) {
      float w = g1_w[(size_t)(kb + j)*64 + o];
      _Float16 hi = (_Float16)w;
      tf[G1H + (size_t)i*8 + j] = hi;
      tf[G1L + (size_t)i*8 + j] = (_Float16)(w - (float)hi);
    }
  }
  for (int i = tid; i < 8*64; i += nt) {
    int l = i & 63, f = i >> 6, mt = f >> 1, ks = f & 1;
    int o = mt*16 + (l & 15), kb = ks*32 + (l >> 4)*8;
    #pragma unroll
    for (int j = 0; j < 8; ++j) {
      float w = g2_w[(size_t)(kb + j)*64 + o];
      _Float16 hi = (_Float16)w;
      tf[G2H + (size_t)i*8 + j] = hi;
      tf[G2L + (size_t)i*8 + j] = (_Float16)(w - (float)hi);
    }
  }
  for (int i = tid; i < 4*64; i += nt) {
    int l = i & 63, f = i >> 6, mt = f >> 1, ks = f & 1;
    int hx = mt*16 + (l & 15), kb = ks*32 + (l >> 4)*8;
    #pragma unroll
    for (int j = 0; j < 8; ++j) {
      float w = h1_w[(size_t)(kb + j)*32 + hx];
      _Float16 hi = (_Float16)w;
      tf[H1H + (size_t)i*8 + j] = hi;
      tf[H1L + (size_t)i*8 + j] = (_Float16)(w - (float)hi);
    }
  }
  for (int i = tid; i < 64; i += nt) {
    int l = i, m = l & 15, kb = (l >> 4)*8;
    #pragma unroll
    for (int j = 0; j < 8; ++j) {
      float w = (m < 3) ? h2_w[(size_t)(kb + j)*3 + m] : 0.f;
      _Float16 hi = (_Float16)w;
      tf[H2H + (size_t)i*8 + j] = hi;
      tf[H2L + (size_t)i*8 + j] = (_Float16)(w - (float)hi);
    }
  }
  for (int i = tid; i < 4*64; i += nt) {
    int l = i & 63, mt = i >> 6;
    int o = mt*16 + (l & 15), kb = (l >> 4)*4;
    #pragma unroll
    for (int j = 0; j < 4; ++j) {
      float acc = 0.f;
      for (int m = 0; m < 64; ++m) acc += Cm[(kb + j)*64 + m]*out_w[m*64 + o];
      _Float16 hi = (_Float16)acc;
      tf[COH + (size_t)i*4 + j] = hi;
      tf[COL + (size_t)i*4 + j] = (_Float16)(acc - (float)hi);
    }
  }
}

// ============================ conv12 + leading fused RNN (split path) ============================
// 512 thr = 8 waves (r9's verified shape: wave = pair, BOTH otiles).
// Blocks [0, NRNN): rnn — 8 waves x 16 batches of register-resident 16x16x16
// MFMA rnn, placed FIRST so their ~20 us serial spans overlap conv work
// (r11 placed them last -> pure tail, conv12 67->131 us regression).
// Blocks [NRNN, NRNN+NB/16): conv1+conv2 for 16 batches each.
__global__ __launch_bounds__(512) void conv12_kernel(
    const float* __restrict__ x, const float* __restrict__ wsr,
    _Float16* __restrict__ a2gh, _Float16* __restrict__ a2gl,
    const float* __restrict__ A, float* __restrict__ hout)
{
  __shared__ __align__(16) _Float16 sW[40960];
  __shared__ __align__(16) _Float16 a1h[16][TS], a1l[16][TS];

  const int tid = threadIdx.x;
  const int lane = tid & 63;
  const int wid = tid >> 6;

  if (blockIdx.x < NRNN) {
    // ---------------- RNN (leading blocks) ----------------
    const int colb = lane & 15;
    const int q = lane >> 4;
    const size_t b = ((size_t)blockIdx.x*8 + wid)*16 + colb;

    const f32x4 av = *(const f32x4*)(A + (size_t)(lane & 15)*16 + q*4);
    half4 Ahi, Alo;
    #pragma unroll
    for (int j = 0; j < 4; ++j) {
      _Float16 hi = (_Float16)av[j];
      Ahi[j] = hi;
      Alo[j] = (_Float16)(av[j] - (float)hi);
    }
    f32x4 pb0 = *(const f32x4*)(wsr + OFF_PB + 0*16 + q*4);
    f32x4 pb1 = *(const f32x4*)(wsr + OFF_PB + 1*16 + q*4);
    f32x4 pb2 = *(const f32x4*)(wsr + OFF_PB + 2*16 + q*4);
    f32x4 pb3 = *(const f32x4*)(wsr + OFF_PB + 3*16 + q*4);
    f32x4 pbb = *(const f32x4*)(wsr + OFF_PBB + q*4);

    const float* xb = x + b*400;
    half4 hh = {}, hl = {};
    f32x4 hf;
    #pragma unroll 2
    for (int t = 0; t < 100; ++t) {
      const f32x4 xv = *(const f32x4*)(xb + t*4);
      f32x4 U;
      #pragma unroll
      for (int r = 0; r < 4; ++r)
        U[r] = pbb[r] + xv[0]*pb0[r] + xv[1]*pb1[r] + xv[2]*pb2[r] + xv[3]*pb3[r];
      f32x4 u = mfma16(Alo, hh, U);
      u = mfma16(Ahi, hl, u);
      u = mfma16(Ahi, hh, u);
      #pragma unroll
      for (int r = 0; r < 4; ++r) {
        float e = __expf(2.f*u[r]);
        float hn = 1.f - 2.f/(e + 1.f);
        hf[r] = hn;
        _Float16 hi = (_Float16)hn;
        hh[r] = hi;
        hl[r] = (_Float16)(hn - (float)hi);
      }
    }
    *(f32x4*)(hout + b*16 + q*4) = hf;
    return;
  }

  // ---------------- conv1 + conv2 (r9 shape) ----------------
  const int n = lane & 15;
  const int nc = (n < 10) ? n : 9;
  const int kh8 = (lane >> 5) * 8;
  const int rq = 4 * (lane >> 5);
  const int lbL = 2*wid + ((lane >> 4) & 1);
  const half8 z8 = {};
  const size_t B0g = (size_t)(blockIdx.x - NRNN) * 16;

  { // stage w2 hi+lo (contiguous in ws)
    const f32x4* src = (const f32x4*)(wsr + OFF_W2H);
    f32x4* dst = (f32x4*)sW;
    for (int i = tid; i < 5120; i += 512) dst[i] = src[i];
  }
  // conv1 for this wave's 2 batches
  {
    const float sc1 = wsr[OFF_SC1 + lane], sh1 = wsr[OFF_SH1 + lane];
    #pragma unroll
    for (int bb = 0; bb < 2; ++bb) {
      const int lb = 2*wid + bb;
      const size_t gb = B0g + lb;
      float xv[4][12];
      #pragma unroll
      for (int c = 0; c < 4; ++c) { xv[c][0] = 0.f; xv[c][11] = 0.f; }
      #pragma unroll
      for (int tt = 0; tt < 10; ++tt)
        #pragma unroll
        for (int c = 0; c < 4; ++c)
          xv[c][1 + tt] = x[gb*400 + (90 + tt)*4 + c];
      float a1[10];
      #pragma unroll
      for (int t = 0; t < 10; ++t) a1[t] = 0.f;
      #pragma unroll
      for (int c = 0; c < 4; ++c)
        #pragma unroll
        for (int k = 0; k < 3; ++k) {
          const float wv = wsr[OFF_W1T + (c*3 + k)*64 + lane];
          #pragma unroll
          for (int t = 0; t < 10; ++t) a1[t] += wv * xv[c][t + k];
        }
      #pragma unroll
      for (int t = 0; t < 10; ++t) {
        float v = sc1*a1[t] + sh1;
        v = v > 0.f ? v : 0.f;
        _Float16 hi = (_Float16)v;
        a1h[lb][t*72 + lane] = hi;
        a1l[lb][t*72 + lane] = (_Float16)(v - (float)hi);
      }
    }
  }
  __syncthreads();

  // conv2 (both otiles)
  {
    f32x16 acc0, acc1;
    #pragma unroll
    for (int r = 0; r < 16; ++r) { acc0[r] = 0.f; acc1[r] = 0.f; }
    const _Float16* bhp = &a1h[lbL][0];
    const _Float16* blp = &a1l[lbL][0];
    #pragma unroll
    for (int sk = 0; sk < 20; ++sk) {
      const int tap = sk >> 2, icb = (sk & 3)*16;
      const int t = nc + tap - 2;
      const int tc = t < 0 ? 0 : (t > 9 ? 9 : t);
      const bool valid = (t >= 0) & (t <= 9);
      const int off = tc*72 + icb + kh8;
      half8 bh = *(const half8*)(bhp + off);
      half8 bl = *(const half8*)(blp + off);
      bh = valid ? bh : z8;
      bl = valid ? bl : z8;
      const half8 wh0 = *(const half8*)(sW + (size_t)(sk*2 + 0)*512 + lane*8);
      const half8 wh1 = *(const half8*)(sW + (size_t)(sk*2 + 1)*512 + lane*8);
      const half8 wl0 = *(const half8*)(sW + (size_t)(40 + sk*2)*512 + lane*8);
      const half8 wl1 = *(const half8*)(sW + (size_t)(41 + sk*2)*512 + lane*8);
      acc0 = mfma32(wh0, bh, acc0);
      acc0 = mfma32(wh0, bl, acc0);
      acc0 = mfma32(wl0, bh, acc0);
      acc1 = mfma32(wh1, bh, acc1);
      acc1 = mfma32(wh1, bl, acc1);
      acc1 = mfma32(wl1, bh, acc1);
    }
    if (n < 10) {
      const size_t gb = B0g + lbL;
      auto epi = [&](const f32x16& ac, int ot) {
        #pragma unroll
        for (int q = 0; q < 4; ++q) {
          const int rowb = 8*q + rq + ot*32;
          const f32x4 sc = *(const f32x4*)(wsr + OFF_SC2 + rowb);
          const f32x4 sh = *(const f32x4*)(wsr + OFF_SH2 + rowb);
          half4 h4, l4;
          #pragma unroll
          for (int r = 0; r < 4; ++r) {
            float v = sc[r]*ac[4*q + r] + sh[r];
            v = v > 0.f ? v : 0.f;
            _Float16 hi = (_Float16)v;
            h4[r] = hi;
            l4[r] = (_Float16)(v - (float)hi);
          }
          *(half4*)(a2gh + gb*640 + n*64 + rowb) = h4;
          *(half4*)(a2gl + gb*640 + n*64 + rowb) = l4;
        }
      };
      epi(acc0, 0);
      epi(acc1, 1);
    }
  }
}

// ============================ conv3 (split path, r9 shape) ============================
// 512 thr = 8 waves; wave w = pair (batches 2w,2w+1), BOTH otiles; grid NB/16.
__global__ __launch_bounds__(512) void conv3k_kernel(
    const float* __restrict__ wsr,
    const _Float16* __restrict__ a2gh, const _Float16* __restrict__ a2gl,
    float* __restrict__ sfp)
{
  __shared__ __align__(16) _Float16 sW[57344];
  __shared__ __align__(16) _Float16 a2h[16][TS], a2l[16][TS];

  const int tid = threadIdx.x;
  const int lane = tid & 63;
  const int wid = tid >> 6;
  const int n = lane & 15;
  const int nc = (n < 10) ? n : 9;
  const int kh8 = (lane >> 5) * 8;
  const int rq = 4 * (lane >> 5);
  const int lbL = 2*wid + ((lane >> 4) & 1);
  const half8 z8 = {};
  const size_t B0g = (size_t)blockIdx.x * 16;

  { // stage w3 hi+lo
    const f32x4* src = (const f32x4*)(wsr + OFF_W3H);
    f32x4* dst = (f32x4*)sW;
    for (int i = tid; i < 7168; i += 512) dst[i] = src[i];
  }
  { // stage a2 from global: 16 batches x 640 halves x 2 planes
    for (int i = tid; i < 1280; i += 512) {
      int idx = i*8;
      int lb = idx / 640, rem = idx % 640;
      int t = rem >> 6, o = rem & 63;
      *(half8*)(&a2h[lb][t*72 + o]) = *(const half8*)(a2gh + (B0g + lb)*640 + rem);
      *(half8*)(&a2l[lb][t*72 + o]) = *(const half8*)(a2gl + (B0g + lb)*640 + rem);
    }
  }
  __syncthreads();

  {
    f32x16 acc0, acc1;
    #pragma unroll
    for (int r = 0; r < 16; ++r) { acc0[r] = 0.f; acc1[r] = 0.f; }
    const _Float16* bhp = &a2h[lbL][0];
    const _Float16* blp = &a2l[lbL][0];
    #pragma unroll
    for (int sk = 0; sk < 28; ++sk) {
      const int tap = sk >> 2, icb = (sk & 3)*16;
      const int t = nc + tap - 3;
      const int tc = t < 0 ? 0 : (t > 9 ? 9 : t);
      const bool valid = (t >= 0) & (t <= 9);
      const int off = tc*72 + icb + kh8;
      half8 bh = *(const half8*)(bhp + off);
      half8 bl = *(const half8*)(blp + off);
      bh = valid ? bh : z8;
      bl = valid ? bl : z8;
      const half8 wh0 = *(const half8*)(sW + (size_t)(sk*2 + 0)*512 + lane*8);
      const half8 wh1 = *(const half8*)(sW + (size_t)(sk*2 + 1)*512 + lane*8);
      const half8 wl0 = *(const half8*)(sW + (size_t)(56 + sk*2)*512 + lane*8);
      const half8 wl1 = *(const half8*)(sW + (size_t)(57 + sk*2)*512 + lane*8);
      acc0 = mfma32(wh0, bh, acc0);
      acc0 = mfma32(wh0, bl, acc0);
      acc0 = mfma32(wl0, bh, acc0);
      acc1 = mfma32(wh1, bh, acc1);
      acc1 = mfma32(wh1, bl, acc1);
      acc1 = mfma32(wl1, bh, acc1);
    }
    auto epi = [&](const f32x16& ac, int ot) {
      #pragma unroll
      for (int q = 0; q < 4; ++q) {
        const int rowb = 8*q + rq + ot*32;
        const f32x4 sc = *(const f32x4*)(wsr + OFF_SC3 + rowb);
        const f32x4 sh = *(const f32x4*)(wsr + OFF_SH3 + rowb);
        f32x4 v;
        #pragma unroll
        for (int r = 0; r < 4; ++r) {
          float t2 = sc[r]*ac[4*q + r] + sh[r];
          t2 = t2 > 0.f ? t2 : 0.f;
          v[r] = (n < 10) ? t2 : 0.f;
        }
        #pragma unroll
        for (int r = 0; r < 4; ++r) {
          v[r] += __shfl_xor(v[r], 1, 16);
          v[r] += __shfl_xor(v[r], 2, 16);
          v[r] += __shfl_xor(v[r], 4, 16);
          v[r] += __shfl_xor(v[r], 8, 16);
        }
        if (n == 0)
          *(f32x4*)(sfp + (B0g + lbL)*64 + rowb) = v * 0.1f;
      }
    };
    epi(acc0, 0);
    epi(acc1, 1);
  }
}

// ============================ conv (fallback: single kernel, r8) ============================
__global__ __launch_bounds__(256) void conv_kernel(
    const float* __restrict__ x, const float* __restrict__ wsr,
    float* __restrict__ sfp)
{
  __shared__ __align__(16) _Float16 sW[57344];
  __shared__ __align__(16) _Float16 a1h[8][TS], a1l[8][TS];
  __shared__ __align__(16) _Float16 a2h[8][TS], a2l[8][TS];

  const int tid = threadIdx.x;
  const int lane = tid & 63;
  const int wid = tid >> 6;
  const int n = lane & 15;
  const int nc = (n < 10) ? n : 9;
  const int kh8 = (lane >> 5) * 8;
  const int rq = 4 * (lane >> 5);
  const int lb0 = (wid >> 1)*4 + (wid & 1)*2;
  const int lbL = lb0 + ((lane >> 4) & 1);
  const half8 z8 = {};
  const float sc1 = wsr[OFF_SC1 + lane], sh1 = wsr[OFF_SH1 + lane];

  for (int it = 0; it < ITER; ++it) {
    const size_t gbase = (size_t)blockIdx.x*(8*ITER) + (size_t)it*8;
    {
      const f32x4* src = (const f32x4*)(wsr + OFF_W2H);
      f32x4* dst = (f32x4*)sW;
      for (int i = tid; i < 5120; i += 256) dst[i] = src[i];
    }
    #pragma unroll
    for (int bb = 0; bb < 2; ++bb) {
      const int lb = lb0 + bb;
      const size_t gb = gbase + lb;
      float xv[4][12];
      #pragma unroll
      for (int c = 0; c < 4; ++c) { xv[c][0] = 0.f; xv[c][11] = 0.f; }
      #pragma unroll
      for (int tt = 0; tt < 10; ++tt)
        #pragma unroll
        for (int c = 0; c < 4; ++c)
          xv[c][1 + tt] = x[gb*400 + (90 + tt)*4 + c];
      float a1[10];
      #pragma unroll
      for (int t = 0; t < 10; ++t) a1[t] = 0.f;
      #pragma unroll
      for (int c = 0; c < 4; ++c)
        #pragma unroll
        for (int k = 0; k < 3; ++k) {
          const float wv = wsr[OFF_W1T + (c*3 + k)*64 + lane];
          #pragma unroll
          for (int t = 0; t < 10; ++t) a1[t] += wv * xv[c][t + k];
        }
      #pragma unroll
      for (int t = 0; t < 10; ++t) {
        float v = sc1*a1[t] + sh1;
        v = v > 0.f ? v : 0.f;
        _Float16 hi = (_Float16)v;
        a1h[lb][t*72 + lane] = hi;
        a1l[lb][t*72 + lane] = (_Float16)(v - (float)hi);
      }
    }
    __syncthreads();
    {
      f32x16 acc0, acc1;
      #pragma unroll
      for (int r = 0; r < 16; ++r) { acc0[r] = 0.f; acc1[r] = 0.f; }
      const _Float16* bhp = &a1h[lbL][0];
      const _Float16* blp = &a1l[lbL][0];
      #pragma unroll
      for (int sk = 0; sk < 20; ++sk) {
        const int tap = sk >> 2, icb = (sk & 3)*16;
        const int t = nc + tap - 2;
        const int tc = t < 0 ? 0 : (t > 9 ? 9 : t);
        const bool valid = (t >= 0) & (t <= 9);
        const int off = tc*72 + icb + kh8;
        half8 bh = *(const half8*)(bhp + off);
        half8 bl = *(const half8*)(blp + off);
        bh = valid ? bh : z8;
        bl = valid ? bl : z8;
        const half8 wh0 = *(const half8*)(sW + (size_t)(sk*2 + 0)*512 + lane*8);
        const half8 wh1 = *(const half8*)(sW + (size_t)(sk*2 + 1)*512 + lane*8);
        const half8 wl0 = *(const half8*)(sW + (size_t)(40 + sk*2)*512 + lane*8);
        const half8 wl1 = *(const half8*)(sW + (size_t)(41 + sk*2)*512 + lane*8);
        acc0 = mfma32(wh0, bh, acc0);
        acc0 = mfma32(wh0, bl, acc0);
        acc0 = mfma32(wl0, bh, acc0);
        acc1 = mfma32(wh1, bh, acc1);
        acc1 = mfma32(wh1, bl, acc1);
        acc1 = mfma32(wl1, bh, acc1);
      }
      if (n < 10) {
        auto epi = [&](const f32x16& ac, int ot) {
          #pragma unroll
          for (int q = 0; q < 4; ++q) {
            const int rowb = 8*q + rq + ot*32;
            const f32x4 sc = *(const f32x4*)(wsr + OFF_SC2 + rowb);
            const f32x4 sh = *(const f32x4*)(wsr + OFF_SH2 + rowb);
            half4 h4, l4;
            #pragma unroll
            for (int r = 0; r < 4; ++r) {
              float v = sc[r]*ac[4*q + r] + sh[r];
              v = v > 0.f ? v : 0.f;
              _Float16 hi = (_Float16)v;
              h4[r] = hi;
              l4[r] = (_Float16)(v - (float)hi);
            }
            *(half4*)(&a2h[lbL][n*72 + rowb]) = h4;
            *(half4*)(&a2l[lbL][n*72 + rowb]) = l4;
          }
        };
        epi(acc0, 0);
        epi(acc1, 1);
      }
    }
    __syncthreads();
    {
      const f32x4* src = (const f32x4*)(wsr + OFF_W3H);
      f32x4* dst = (f32x4*)sW;
      for (int i = tid; i < 7168; i += 256) dst[i] = src[i];
    }
    __syncthreads();
    {
      f32x16 acc0, acc1;
      #pragma unroll
      for (int r = 0; r < 16; ++r) { acc0[r] = 0.f; acc1[r] = 0.f; }
      const _Float16* bhp = &a2h[lbL][0];
      const _Float16* blp = &a2l[lbL][0];
      #pragma unroll
      for (int sk = 0; sk < 28; ++sk) {
        const int tap = sk >> 2, icb = (sk & 3)*16;
        const int t = nc + tap - 3;
        const int tc = t < 0 ? 0 : (t > 9 ? 9 : t);
        const bool valid = (t >= 0) & (t <= 9);
        const int off = tc*72 + icb + kh8;
        half8 bh = *(const half8*)(bhp + off);
        half8 bl = *(const half8*)(blp + off);
        bh = valid ? bh : z8;
        bl = valid ? bl : z8;
        const half8 wh0 = *(const half8*)(sW + (size_t)(sk*2 + 0)*512 + lane*8);
        const half8 wh1 = *(const half8*)(sW + (size_t)(sk*2 + 1)*512 + lane*8);
        const half8 wl0 = *(const half8*)(sW + (size_t)(56 + sk*2)*512 + lane*8);
        const half8 wl1 = *(const half8*)(sW + (size_t)(57 + sk*2)*512 + lane*8);
        acc0 = mfma32(wh0, bh, acc0);
        acc0 = mfma32(wh0, bl, acc0);
        acc0 = mfma32(wl0, bh, acc0);
        acc1 = mfma32(wh1, bh, acc1);
        acc1 = mfma32(wh1, bl, acc1);
        acc1 = mfma32(wl1, bh, acc1);
      }
      auto epi = [&](const f32x16& ac, int ot) {
        #pragma unroll
        for (int q = 0; q < 4; ++q) {
          const int rowb = 8*q + rq + ot*32;
          const f32x4 sc = *(const f32x4*)(wsr + OFF_SC3 + rowb);
          const f32x4 sh = *(const f32x4*)(wsr + OFF_SH3 + rowb);
          f32x4 v;
          #pragma unroll
          for (int r = 0; r < 4; ++r) {
            float t2 = sc[r]*ac[4*q + r] + sh[r];
            t2 = t2 > 0.f ? t2 : 0.f;
            v[r] = (n < 10) ? t2 : 0.f;
          }
          #pragma unroll
          for (int r = 0; r < 4; ++r) {
            v[r] += __shfl_xor(v[r], 1, 16);
            v[r] += __shfl_xor(v[r], 2, 16);
            v[r] += __shfl_xor(v[r], 4, 16);
            v[r] += __shfl_xor(v[r], 8, 16);
          }
          if (n == 0)
            *(f32x4*)(sfp + (gbase + lbL)*64 + rowb) = v * 0.1f;
        }
      };
      epi(acc0, 0);
      epi(acc1, 1);
    }
    __syncthreads();
  }
}

// ============================ RNN (standalone, for fallback path) ============================
__global__ __launch_bounds__(256) void rnn_kernel(
    const float* __restrict__ x, const float* __restrict__ wsr,
    const float* __restrict__ A, float* __restrict__ hout)
{
  const int lane = threadIdx.x & 63;
  const int wid = threadIdx.x >> 6;
  const int colb = lane & 15;
  const int q = lane >> 4;
  const size_t b = ((size_t)blockIdx.x*4 + wid)*16 + colb;

  const f32x4 av = *(const f32x4*)(A + (size_t)(lane & 15)*16 + q*4);
  half4 Ahi, Alo;
  #pragma unroll
  for (int j = 0; j < 4; ++j) {
    _Float16 hi = (_Float16)av[j];
    Ahi[j] = hi;
    Alo[j] = (_Float16)(av[j] - (float)hi);
  }
  f32x4 pb0 = *(const f32x4*)(wsr + OFF_PB + 0*16 + q*4);
  f32x4 pb1 = *(const f32x4*)(wsr + OFF_PB + 1*16 + q*4);
  f32x4 pb2 = *(const f32x4*)(wsr + OFF_PB + 2*16 + q*4);
  f32x4 pb3 = *(const f32x4*)(wsr + OFF_PB + 3*16 + q*4);
  f32x4 pbb = *(const f32x4*)(wsr + OFF_PBB + q*4);

  const float* xb = x + b*400;
  half4 hh = {}, hl = {};
  f32x4 hf;
  #pragma unroll 2
  for (int t = 0; t < 100; ++t) {
    const f32x4 xv = *(const f32x4*)(xb + t*4);
    f32x4 U;
    #pragma unroll
    for (int r = 0; r < 4; ++r)
      U[r] = pbb[r] + xv[0]*pb0[r] + xv[1]*pb1[r] + xv[2]*pb2[r] + xv[3]*pb3[r];
    f32x4 u = mfma16(Alo, hh, U);
    u = mfma16(Ahi, hl, u);
    u = mfma16(Ahi, hh, u);
    #pragma unroll
    for (int r = 0; r < 4; ++r) {
      float e = __expf(2.f*u[r]);
      float hn = 1.f - 2.f/(e + 1.f);
      hf[r] = hn;
      _Float16 hi = (_Float16)hn;
      hh[r] = hi;
      hl[r] = (_Float16)(hn - (float)hi);
    }
  }
  *(f32x4*)(hout + b*16 + q*4) = hf;
}

// ============================ tail (MFMA, 16 batches/wave) ============================
#define CMBH 0
#define CMBL 2176
#define T1H  4352
#define T1L  5504
#define FLH  6656
#define FLL  7808
#define RH   8960
#define RL   9600
__global__ __launch_bounds__(256) void tail_kernel(
    const float* __restrict__ wsr,
    const float* __restrict__ g1_b, const float* __restrict__ g2_b,
    const float* __restrict__ h1_b, const float* __restrict__ h2_b,
    const float* __restrict__ out_b, float* __restrict__ out)
{
  __shared__ __align__(16) _Float16 sWF[TFH];
  __shared__ __align__(16) _Float16 sAct[4*10240];

  const int tid = threadIdx.x;
  const int lane = tid & 63;
  const int wid = tid >> 6;
  const int n = lane & 15;
  const int q = lane >> 4;
  const int B0 = blockIdx.x*64 + wid*16;

  {
    const f32x4* src = (const f32x4*)(wsr + OFF_TF);
    f32x4* dst = (f32x4*)sWF;
    for (int i = tid; i < TFH/8; i += 256) dst[i] = src[i];
  }
  __syncthreads();

  _Float16* wa = sAct + wid*10240;
  const float* sf = wsr + OFF_SF;
  const float* hws = wsr + OFF_H;

  const f32x4 hv = *(const f32x4*)(hws + (size_t)(B0 + n)*16 + q*4);
  half4 hh, hl;
  #pragma unroll
  for (int j = 0; j < 4; ++j) {
    _Float16 hi = (_Float16)hv[j];
    hh[j] = hi;
    hl[j] = (_Float16)(hv[j] - (float)hi);
  }
  f32x4 lc[4];
  #pragma unroll
  for (int mt = 0; mt < 4; ++mt) {
    lc[mt] = *(const f32x4*)(out_b + mt*16 + q*4);
    const half4 ah = *(const half4*)(sWF + COH + (size_t)(mt*64 + lane)*4);
    const half4 al = *(const half4*)(sWF + COL + (size_t)(mt*64 + lane)*4);
    lc[mt] = mfma16(al, hh, lc[mt]);
    lc[mt] = mfma16(ah, hl, lc[mt]);
    lc[mt] = mfma16(ah, hh, lc[mt]);
  }
  f32x4 sfv[4];
  #pragma unroll
  for (int mt = 0; mt < 4; ++mt) {
    sfv[mt] = *(const f32x4*)(sf + (size_t)(B0 + n)*64 + mt*16 + q*4);
    half4 sh4, sl4, lh4, ll4;
    #pragma unroll
    for (int r = 0; r < 4; ++r) {
      _Float16 hi = (_Float16)sfv[mt][r];
      sh4[r] = hi; sl4[r] = (_Float16)(sfv[mt][r] - (float)hi);
      _Float16 hi2 = (_Float16)lc[mt][r];
      lh4[r] = hi2; ll4[r] = (_Float16)(lc[mt][r] - (float)hi2);
    }
    *(half4*)(wa + CMBH + n*136 + mt*16 + q*4) = sh4;
    *(half4*)(wa + CMBL + n*136 + mt*16 + q*4) = sl4;
    *(half4*)(wa + CMBH + n*136 + 64 + mt*16 + q*4) = lh4;
    *(half4*)(wa + CMBL + n*136 + 64 + mt*16 + q*4) = ll4;
  }
  f32x4 u1[4];
  #pragma unroll
  for (int mt = 0; mt < 4; ++mt) u1[mt] = *(const f32x4*)(g1_b + mt*16 + q*4);
  #pragma unroll
  for (int ks = 0; ks < 4; ++ks) {
    const half8 bh = *(const half8*)(wa + CMBH + n*136 + ks*32 + q*8);
    const half8 bl = *(const half8*)(wa + CMBL + n*136 + ks*32 + q*8);
    #pragma unroll
    for (int mt = 0; mt < 4; ++mt) {
      const half8 ah = *(const half8*)(sWF + G1H + (size_t)((mt*4 + ks)*64 + lane)*8);
      const half8 al = *(const half8*)(sWF + G1L + (size_t)((mt*4 + ks)*64 + lane)*8);
      u1[mt] = mfma16k32(al, bh, u1[mt]);
      u1[mt] = mfma16k32(ah, bl, u1[mt]);
      u1[mt] = mfma16k32(ah, bh, u1[mt]);
    }
  }
  #pragma unroll
  for (int mt = 0; mt < 4; ++mt) {
    half4 th4, tl4;
    #pragma unroll
    for (int r = 0; r < 4; ++r) {
      float e = __expf(2.f*u1[mt][r]);
      float t1 = 1.f - 2.f/(e + 1.f);
      _Float16 hi = (_Float16)t1;
      th4[r] = hi; tl4[r] = (_Float16)(t1 - (float)hi);
    }
    *(half4*)(wa + T1H + n*72 + mt*16 + q*4) = th4;
    *(half4*)(wa + T1L + n*72 + mt*16 + q*4) = tl4;
  }
  f32x4 u2[4];
  #pragma unroll
  for (int mt = 0; mt < 4; ++mt) u2[mt] = *(const f32x4*)(g2_b + mt*16 + q*4);
  #pragma unroll
  for (int ks = 0; ks < 2; ++ks) {
    const half8 bh = *(const half8*)(wa + T1H + n*72 + ks*32 + q*8);
    const half8 bl = *(const half8*)(wa + T1L + n*72 + ks*32 + q*8);
    #pragma unroll
    for (int mt = 0; mt < 4; ++mt) {
      const half8 ah = *(const half8*)(sWF + G2H + (size_t)((mt*2 + ks)*64 + lane)*8);
      const half8 al = *(const half8*)(sWF + G2L + (size_t)((mt*2 + ks)*64 + lane)*8);
      u2[mt] = mfma16k32(al, bh, u2[mt]);
      u2[mt] = mfma16k32(ah, bl, u2[mt]);
      u2[mt] = mfma16k32(ah, bh, u2[mt]);
    }
  }
  #pragma unroll
  for (int mt = 0; mt < 4; ++mt) {
    half4 fh4, fl4;
    #pragma unroll
    for (int r = 0; r < 4; ++r) {
      float gate = 1.f/(1.f + __expf(-u2[mt][r]));
      float f = sfv[mt][r] * gate;
      _Float16 hi = (_Float16)f;
      fh4[r] = hi; fl4[r] = (_Float16)(f - (float)hi);
    }
    *(half4*)(wa + FLH + n*72 + mt*16 + q*4) = fh4;
    *(half4*)(wa + FLL + n*72 + mt*16 + q*4) = fl4;
  }
  f32x4 u3[2];
  #pragma unroll
  for (int mt = 0; mt < 2; ++mt) u3[mt] = *(const f32x4*)(h1_b + mt*16 + q*4);
  #pragma unroll
  for (int ks = 0; ks < 2; ++ks) {
    const half8 bh = *(const half8*)(wa + FLH + n*72 + ks*32 + q*8);
    const half8 bl = *(const half8*)(wa + FLL + n*72 + ks*32 + q*8);
    #pragma unroll
    for (int mt = 0; mt < 2; ++mt) {
      const half8 ah = *(const half8*)(sWF + H1H + (size_t)((mt*2 + ks)*64 + lane)*8);
      const half8 al = *(const half8*)(sWF + H1L + (size_t)((mt*2 + ks)*64 + lane)*8);
      u3[mt] = mfma16k32(al, bh, u3[mt]);
      u3[mt] = mfma16k32(ah, bl, u3[mt]);
      u3[mt] = mfma16k32(ah, bh, u3[mt]);
    }
  }
  #pragma unroll
  for (int mt = 0; mt < 2; ++mt) {
    half4 rh4, rl4;
    #pragma unroll
    for (int r = 0; r < 4; ++r) {
      float v = fmaxf(u3[mt][r], 0.f);
      _Float16 hi = (_Float16)v;
      rh4[r] = hi; rl4[r] = (_Float16)(v - (float)hi);
    }
    *(half4*)(wa + RH + n*40 + mt*16 + q*4) = rh4;
    *(half4*)(wa + RL + n*40 + mt*16 + q*4) = rl4;
  }
  {
    f32x4 u4;
    if (q == 0) { u4[0] = h2_b[0]; u4[1] = h2_b[1]; u4[2] = h2_b[2]; u4[3] = 0.f; }
    else { u4[0] = 0.f; u4[1] = 0.f; u4[2] = 0.f; u4[3] = 0.f; }
    const half8 bh = *(const half8*)(wa + RH + n*40 + q*8);
    const half8 bl = *(const half8*)(wa + RL + n*40 + q*8);
    const half8 ah = *(const half8*)(sWF + H2H + (size_t)lane*8);
    const half8 al = *(const half8*)(sWF + H2L + (size_t)lane*8);
    u4 = mfma16k32(al, bh, u4);
    u4 = mfma16k32(ah, bl, u4);
    u4 = mfma16k32(ah, bh, u4);
    if (q == 0) {
      out[(size_t)(B0 + n)*3 + 0] = u4[0];
      out[(size_t)(B0 + n)*3 + 1] = u4[1];
      out[(size_t)(B0 + n)*3 + 2] = u4[2];
    }
  }
}

// ============================ launch ============================
extern "C" void kernel_launch(void* const* d_in, const int* in_sizes, int n_in,
                              void* d_out, int out_size, void* d_ws, size_t ws_size,
                              hipStream_t stream) {
  const float* x       = (const float*)d_in[0];
  const float* conv1_w = (const float*)d_in[1];
  const float* conv1_b = (const float*)d_in[2];
  const float* conv2_w = (const float*)d_in[3];
  const float* conv2_b = (const float*)d_in[4];
  const float* conv3_w = (const float*)d_in[5];
  const float* conv3_b = (const float*)d_in[6];
  const float* bn1_g   = (const float*)d_in[7];
  const float* bn1_b   = (const float*)d_in[8];
  const float* bn2_g   = (const float*)d_in[9];
  const float* bn2_b   = (const float*)d_in[10];
  const float* bn3_g   = (const float*)d_in[11];
  const float* bn3_b   = (const float*)d_in[12];
  const float* proj_w  = (const float*)d_in[13];
  const float* proj_b  = (const float*)d_in[14];
  const float* A       = (const float*)d_in[15];
  const float* Bm      = (const float*)d_in[16];
  const float* Cm      = (const float*)d_in[17];
  const float* out_w   = (const float*)d_in[18];
  const float* out_b   = (const float*)d_in[19];
  const float* g1_w    = (const float*)d_in[20];
  const float* g1_b    = (const float*)d_in[21];
  const float* g2_w    = (const float*)d_in[22];
  const float* g2_b    = (const float*)d_in[23];
  const float* h1_w    = (const float*)d_in[24];
  const float* h1_b    = (const float*)d_in[25];
  const float* h2_w    = (const float*)d_in[26];
  const float* h2_b    = (const float*)d_in[27];
  float* ws = (float*)d_ws;
  float* out = (float*)d_out;

  prep_kernel<<<64, 256, 0, stream>>>(conv1_w, conv1_b, conv2_w, conv2_b,
      conv3_w, conv3_b, bn1_g, bn1_b, bn2_g, bn2_b, bn3_g, bn3_b,
      proj_w, proj_b, A, Bm, Cm, out_w, g1_w, g2_w, h1_w, h2_w, ws);

  if (ws_size >= WS_NEED) {
    _Float16* a2gh = (_Float16*)(ws + OFF_A2);
    _Float16* a2gl = a2gh + (size_t)NB*640;
    conv12_kernel<<<NRNN + NB/16, 512, 0, stream>>>(x, ws, a2gh, a2gl,
        A, ws + OFF_H);
    conv3k_kernel<<<NB/16, 512, 0, stream>>>(ws, a2gh, a2gl, ws + OFF_SF);
  } else {
    conv_kernel<<<NB/(8*ITER), 256, 0, stream>>>(x, ws, ws + OFF_SF);
    rnn_kernel<<<NB/64, 256, 0, stream>>>(x, ws, A, ws + OFF_H);
  }
  tail_kernel<<<NB/64, 256, 0, stream>>>(ws, g1_b, g2_b, h1_b, h2_b, out_b, out);
}